// Round 1
// baseline (1217.106 us; speedup 1.0000x reference)
//
#include <hip/hip_runtime.h>

#define D 64

// ---------------------------------------------------------------------------
// Kernel 1: nf_out = relu(nf @ W_node + bias_node)       [N,64]@[64,64]
// ---------------------------------------------------------------------------
__global__ __launch_bounds__(256) void node_proj_kernel(
    const float* __restrict__ nf, const float* __restrict__ W,
    const float* __restrict__ bias, float* __restrict__ out, int N)
{
    constexpr int ROWS = 16;
    __shared__ float Ws[D * D];
    __shared__ float As[ROWS * D];
    const int tid = threadIdx.x;
    const long row0 = (long)blockIdx.x * ROWS;

    #pragma unroll
    for (int i = tid; i < D * D / 4; i += 256)
        ((float4*)Ws)[i] = ((const float4*)W)[i];
    {
        int i = tid;  // ROWS*D/4 == 256, exactly one float4 per thread
        long r = row0 + (i * 4) / D;
        ((float4*)As)[i] = (r < N) ? ((const float4*)nf)[row0 * D / 4 + i]
                                   : make_float4(0.f, 0.f, 0.f, 0.f);
    }
    __syncthreads();

    const int c = tid & 63;
    const float b = bias[c];
    for (int rr = tid >> 6; rr < ROWS; rr += 4) {
        float acc = 0.f;
        #pragma unroll
        for (int k = 0; k < D; ++k)
            acc = fmaf(As[rr * D + k], Ws[k * D + c], acc);
        long r = row0 + rr;
        if (r < N) out[r * D + c] = fmaxf(acc + b, 0.f);
    }
}

// ---------------------------------------------------------------------------
// Kernel 2: ef_h = ef @ W_edge; atomicAdd into nb_sum[dst], deg[dst]
// ---------------------------------------------------------------------------
__global__ __launch_bounds__(256) void edge_proj_accum_kernel(
    const float* __restrict__ ef, const int* __restrict__ dst,
    const float* __restrict__ W, float* __restrict__ nb_sum,
    float* __restrict__ deg, int E)
{
    constexpr int ROWS = 32;
    __shared__ float Ws[D * D];
    __shared__ float As[ROWS * D];
    __shared__ int dsts[ROWS];
    const int tid = threadIdx.x;
    const long row0 = (long)blockIdx.x * ROWS;

    #pragma unroll
    for (int i = tid; i < D * D / 4; i += 256)
        ((float4*)Ws)[i] = ((const float4*)W)[i];
    #pragma unroll
    for (int i = tid; i < ROWS * D / 4; i += 256) {
        long r = row0 + (i * 4) / D;
        ((float4*)As)[i] = (r < E) ? ((const float4*)ef)[row0 * D / 4 + i]
                                   : make_float4(0.f, 0.f, 0.f, 0.f);
    }
    if (tid < ROWS) {
        long r = row0 + tid;
        int dv = (r < E) ? dst[r] : -1;
        dsts[tid] = dv;
        if (dv >= 0) atomicAdd(deg + dv, 1.0f);
    }
    __syncthreads();

    const int c = tid & 63;
    for (int rr = tid >> 6; rr < ROWS; rr += 4) {
        float acc = 0.f;
        #pragma unroll
        for (int k = 0; k < D; ++k)
            acc = fmaf(As[rr * D + k], Ws[k * D + c], acc);
        int dv = dsts[rr];
        if (dv >= 0) atomicAdd(nb_sum + (long)dv * D + c, acc);
    }
}

// ---------------------------------------------------------------------------
// Kernel 3: nb = nb_sum / max(deg, 1)
// ---------------------------------------------------------------------------
__global__ __launch_bounds__(256) void finalize_nb_kernel(
    float* __restrict__ nb, const float* __restrict__ deg, long total)
{
    long i = (long)blockIdx.x * 256 + threadIdx.x;
    if (i < total) {
        float d = deg[i >> 6];
        nb[i] *= 1.0f / fmaxf(d, 1.0f);
    }
}

// ---------------------------------------------------------------------------
// Kernel 4: recompute ef_h; tmp = ef_h + nb[dst]; sd = 0.5*(nf_out[src]+nf_out[dst]);
//           ef_out = relu(concat(tmp, sd) @ W_dense + b_dense + bias_edge)
// ---------------------------------------------------------------------------
__global__ __launch_bounds__(256) void edge_out_kernel(
    const float* __restrict__ ef, const int* __restrict__ src,
    const int* __restrict__ dst, const float* __restrict__ W_edge,
    const float* __restrict__ nb, const float* __restrict__ nf_out,
    const float* __restrict__ W_dense, const float* __restrict__ b_dense,
    const float* __restrict__ bias_edge, float* __restrict__ out, int E)
{
    constexpr int ROWS = 32;
    __shared__ float We[D * D];          // 16 KB
    __shared__ float Wd[2 * D * D];      // 32 KB
    __shared__ float As[ROWS * D];       // 8 KB
    __shared__ float Cat[ROWS * 2 * D];  // 16 KB
    __shared__ int sidx[ROWS], didx[ROWS];
    const int tid = threadIdx.x;
    const long row0 = (long)blockIdx.x * ROWS;

    #pragma unroll
    for (int i = tid; i < D * D / 4; i += 256)
        ((float4*)We)[i] = ((const float4*)W_edge)[i];
    #pragma unroll
    for (int i = tid; i < 2 * D * D / 4; i += 256)
        ((float4*)Wd)[i] = ((const float4*)W_dense)[i];
    #pragma unroll
    for (int i = tid; i < ROWS * D / 4; i += 256) {
        long r = row0 + (i * 4) / D;
        ((float4*)As)[i] = (r < E) ? ((const float4*)ef)[row0 * D / 4 + i]
                                   : make_float4(0.f, 0.f, 0.f, 0.f);
    }
    if (tid < ROWS) {
        long r = row0 + tid;
        sidx[tid] = (r < E) ? src[r] : 0;
        didx[tid] = (r < E) ? dst[r] : 0;
    }
    __syncthreads();

    const int c = tid & 63;
    // phase 1: build concat rows
    for (int rr = tid >> 6; rr < ROWS; rr += 4) {
        float acc = 0.f;
        #pragma unroll
        for (int k = 0; k < D; ++k)
            acc = fmaf(As[rr * D + k], We[k * D + c], acc);
        int s = sidx[rr], dv = didx[rr];
        Cat[rr * 2 * D + c]     = acc + nb[(long)dv * D + c];
        Cat[rr * 2 * D + D + c] = 0.5f * (nf_out[(long)s * D + c] + nf_out[(long)dv * D + c]);
    }
    __syncthreads();

    // phase 2: dense [ROWS,128] @ [128,64]
    const float b = b_dense[c] + bias_edge[c];
    for (int rr = tid >> 6; rr < ROWS; rr += 4) {
        float acc = 0.f;
        #pragma unroll
        for (int k = 0; k < 2 * D; ++k)
            acc = fmaf(Cat[rr * 2 * D + k], Wd[k * D + c], acc);
        long r = row0 + rr;
        if (r < E) out[r * D + c] = fmaxf(acc + b, 0.f);
    }
}

// ---------------------------------------------------------------------------
extern "C" void kernel_launch(void* const* d_in, const int* in_sizes, int n_in,
                              void* d_out, int out_size, void* d_ws, size_t ws_size,
                              hipStream_t stream) {
    const float* nf        = (const float*)d_in[0];
    const float* ef        = (const float*)d_in[1];
    const int*   src       = (const int*)d_in[2];
    const int*   dst       = (const int*)d_in[3];
    const float* W_node    = (const float*)d_in[4];
    const float* W_edge    = (const float*)d_in[5];
    const float* bias_node = (const float*)d_in[6];
    const float* bias_edge = (const float*)d_in[7];
    const float* W_dense   = (const float*)d_in[8];
    const float* b_dense   = (const float*)d_in[9];

    const int N = in_sizes[0] / D;
    const int E = in_sizes[1] / D;

    float* nf_out = (float*)d_out;
    float* ef_out = (float*)d_out + (size_t)N * D;

    float* nb  = (float*)d_ws;            // N*D floats
    float* deg = nb + (size_t)N * D;      // N floats

    hipMemsetAsync(d_ws, 0, ((size_t)N * D + N) * sizeof(float), stream);

    node_proj_kernel<<<(N + 15) / 16, 256, 0, stream>>>(nf, W_node, bias_node, nf_out, N);
    edge_proj_accum_kernel<<<(E + 31) / 32, 256, 0, stream>>>(ef, dst, W_edge, nb, deg, E);
    finalize_nb_kernel<<<(int)(((size_t)N * D + 255) / 256), 256, 0, stream>>>(nb, deg, (long)N * D);
    edge_out_kernel<<<(E + 31) / 32, 256, 0, stream>>>(ef, src, dst, W_edge, nb, nf_out,
                                                       W_dense, b_dense, bias_edge, ef_out, E);
}

// Round 2
// 467.705 us; speedup vs baseline: 2.6023x; 2.6023x over previous
//
#include <hip/hip_runtime.h>

#define D 64
#define LDA 72    // bf16 row stride for 64-wide tiles: 144 B = 9*16 (16B-aligned rows, 2-way-bank free)
#define LDA2 136  // bf16 row stride for 128-wide tiles: 272 B = 17*16

typedef __attribute__((ext_vector_type(8))) short short8;
typedef __attribute__((ext_vector_type(4))) float f32x4;

__device__ __forceinline__ ushort f2b(float f) {
    union { float f; unsigned u; } x; x.f = f;
    unsigned r = x.u + 0x7FFFu + ((x.u >> 16) & 1u);   // RNE to bf16
    return (ushort)(r >> 16);
}
__device__ __forceinline__ float b2f(ushort u) {
    union { float f; unsigned u; } x; x.u = ((unsigned)u) << 16;
    return x.f;
}
__device__ __forceinline__ short8 pack8(float4 a, float4 b) {
    short8 r;
    r[0] = (short)f2b(a.x); r[1] = (short)f2b(a.y); r[2] = (short)f2b(a.z); r[3] = (short)f2b(a.w);
    r[4] = (short)f2b(b.x); r[5] = (short)f2b(b.y); r[6] = (short)f2b(b.z); r[7] = (short)f2b(b.w);
    return r;
}

// ---------------------------------------------------------------------------
// Kernel 1: nf_out = relu(nf @ W_node + bias_node)   [N,64]@[64,64] — small,
// keep the (working) vector-f32 version; ~2% of total time.
// ---------------------------------------------------------------------------
__global__ __launch_bounds__(256) void node_proj_kernel(
    const float* __restrict__ nf, const float* __restrict__ W,
    const float* __restrict__ bias, float* __restrict__ out, int N)
{
    constexpr int ROWS = 16;
    __shared__ float Ws[D * D];
    __shared__ float As[ROWS * D];
    const int tid = threadIdx.x;
    const long row0 = (long)blockIdx.x * ROWS;

    #pragma unroll
    for (int i = tid; i < D * D / 4; i += 256)
        ((float4*)Ws)[i] = ((const float4*)W)[i];
    {
        int i = tid;  // ROWS*D/4 == 256
        long r = row0 + (i * 4) / D;
        ((float4*)As)[i] = (r < N) ? ((const float4*)nf)[row0 * D / 4 + i]
                                   : make_float4(0.f, 0.f, 0.f, 0.f);
    }
    __syncthreads();

    const int c = tid & 63;
    const float b = bias[c];
    for (int rr = tid >> 6; rr < ROWS; rr += 4) {
        float acc = 0.f;
        #pragma unroll
        for (int k = 0; k < D; ++k)
            acc = fmaf(As[rr * D + k], Ws[k * D + c], acc);
        long r = row0 + rr;
        if (r < N) out[r * D + c] = fmaxf(acc + b, 0.f);
    }
}

// ---------------------------------------------------------------------------
// Kernel 2 (MFMA): ef_h = ef @ W_edge (bf16 MFMA); atomicAdd into nb_sum[dst], deg[dst]
// Block = 256 thr (4 waves), 64 edges. Wave w owns rows 16w..16w+15.
// mfma_f32_16x16x32_bf16 layouts: A row=lane&15, k=8*(lane>>4)+j;
// B col=lane&15, k=8*(lane>>4)+j; D col=lane&15, row=4*(lane>>4)+reg.
// ---------------------------------------------------------------------------
__global__ __launch_bounds__(256) void edge_proj_accum_kernel(
    const float* __restrict__ ef, const int* __restrict__ dst,
    const float* __restrict__ W, float* __restrict__ nb_sum,
    float* __restrict__ deg, int E)
{
    __shared__ ushort A1[64 * LDA];   // bf16(ef rows)
    __shared__ ushort Bw[64 * LDA];   // Bw[n][k] = bf16(W[k][n])
    __shared__ int dsts[64];
    const int tid = threadIdx.x;
    const long row0 = (long)blockIdx.x * 64;

    {   // stage W -> Bw[n][k] (transpose), 16 elems/thread
        int k = tid >> 2, n0 = (tid & 3) * 16;
        const float4* wr = (const float4*)(W + (long)k * D + n0);
        float4 v0 = wr[0], v1 = wr[1], v2 = wr[2], v3 = wr[3];
        float vs[16] = {v0.x, v0.y, v0.z, v0.w, v1.x, v1.y, v1.z, v1.w,
                        v2.x, v2.y, v2.z, v2.w, v3.x, v3.y, v3.z, v3.w};
        #pragma unroll
        for (int j = 0; j < 16; ++j) Bw[(n0 + j) * LDA + k] = f2b(vs[j]);
    }
    {   // stage A1 rows (bf16), 16 elems/thread
        int r = tid >> 2, c0 = (tid & 3) * 16;
        long er = row0 + r; if (er >= E) er = E - 1;
        const float4* sp = (const float4*)(ef + er * D + c0);
        float4 v0 = sp[0], v1 = sp[1], v2 = sp[2], v3 = sp[3];
        *(short8*)&A1[r * LDA + c0]     = pack8(v0, v1);
        *(short8*)&A1[r * LDA + c0 + 8] = pack8(v2, v3);
    }
    if (tid < 64) {
        long er = row0 + tid;
        int dv = (er < E) ? dst[er] : -1;
        dsts[tid] = dv;
        if (dv >= 0) atomicAdd(deg + dv, 1.0f);
    }
    __syncthreads();

    const int w = tid >> 6, lane = tid & 63;
    const int lr = lane & 15, g = lane >> 4;

    short8 a0 = *(const short8*)&A1[(16 * w + lr) * LDA + 8 * g];
    short8 a1 = *(const short8*)&A1[(16 * w + lr) * LDA + 32 + 8 * g];

    f32x4 acc[4];
    #pragma unroll
    for (int t = 0; t < 4; ++t) {
        f32x4 z = {0.f, 0.f, 0.f, 0.f};
        short8 b0 = *(const short8*)&Bw[(16 * t + lr) * LDA + 8 * g];
        short8 b1 = *(const short8*)&Bw[(16 * t + lr) * LDA + 32 + 8 * g];
        z = __builtin_amdgcn_mfma_f32_16x16x32_bf16(a0, b0, z, 0, 0, 0);
        z = __builtin_amdgcn_mfma_f32_16x16x32_bf16(a1, b1, z, 0, 0, 0);
        acc[t] = z;
    }
    #pragma unroll
    for (int t = 0; t < 4; ++t) {
        int c = 16 * t + lr;
        #pragma unroll
        for (int reg = 0; reg < 4; ++reg) {
            int r = 16 * w + 4 * g + reg;
            int dv = dsts[r];
            if (dv >= 0) atomicAdd(nb_sum + (long)dv * D + c, acc[t][reg]);
        }
    }
}

// ---------------------------------------------------------------------------
// Kernel 3: nb = nb_sum / max(deg, 1)
// ---------------------------------------------------------------------------
__global__ __launch_bounds__(256) void finalize_nb_kernel(
    float* __restrict__ nb, const float* __restrict__ deg, long total)
{
    long i = (long)blockIdx.x * 256 + threadIdx.x;
    if (i < total) {
        float d = deg[i >> 6];
        nb[i] *= 1.0f / fmaxf(d, 1.0f);
    }
}

// ---------------------------------------------------------------------------
// Kernel 4 (MFMA): ef_h = ef@W_edge; A2 = bf16 concat(ef_h + nb[dst], 0.5*(nf[src]+nf[dst]));
// ef_out = relu(A2 @ W_dense + b_dense + bias_edge).   64 edges/block, 4 waves.
// LDS = 53.8 KB -> 3 blocks/CU.
// ---------------------------------------------------------------------------
__global__ __launch_bounds__(256) void edge_out_kernel(
    const float* __restrict__ ef, const int* __restrict__ src,
    const int* __restrict__ dst, const float* __restrict__ W_edge,
    const float* __restrict__ nb, const float* __restrict__ nf_out,
    const float* __restrict__ W_dense, const float* __restrict__ b_dense,
    const float* __restrict__ bias_edge, float* __restrict__ out, int E)
{
    __shared__ ushort A1[64 * LDA];    // bf16(ef rows)                9216 B
    __shared__ ushort Bw[64 * LDA];    // W_edge  [n][k]               9216 B
    __shared__ ushort Bd[64 * LDA2];   // W_dense [n][k], k=0..127    17408 B
    __shared__ ushort A2[64 * LDA2];   // concat tile                 17408 B
    const int tid = threadIdx.x;
    const long row0 = (long)blockIdx.x * 64;

    {   // stage W_edge -> Bw[n][k]
        int k = tid >> 2, n0 = (tid & 3) * 16;
        const float4* wr = (const float4*)(W_edge + (long)k * D + n0);
        float4 v0 = wr[0], v1 = wr[1], v2 = wr[2], v3 = wr[3];
        float vs[16] = {v0.x, v0.y, v0.z, v0.w, v1.x, v1.y, v1.z, v1.w,
                        v2.x, v2.y, v2.z, v2.w, v3.x, v3.y, v3.z, v3.w};
        #pragma unroll
        for (int j = 0; j < 16; ++j) Bw[(n0 + j) * LDA + k] = f2b(vs[j]);
    }
    {   // stage W_dense (128x64) -> Bd[n][k], 32 elems/thread
        int k = tid >> 1, n0 = (tid & 1) * 32;
        const float4* wr = (const float4*)(W_dense + (long)k * D + n0);
        #pragma unroll
        for (int q = 0; q < 8; ++q) {
            float4 v = wr[q];
            Bd[(n0 + 4 * q + 0) * LDA2 + k] = f2b(v.x);
            Bd[(n0 + 4 * q + 1) * LDA2 + k] = f2b(v.y);
            Bd[(n0 + 4 * q + 2) * LDA2 + k] = f2b(v.z);
            Bd[(n0 + 4 * q + 3) * LDA2 + k] = f2b(v.w);
        }
    }
    {   // stage A1 rows
        int r = tid >> 2, c0 = (tid & 3) * 16;
        long er = row0 + r; if (er >= E) er = E - 1;
        const float4* sp = (const float4*)(ef + er * D + c0);
        float4 v0 = sp[0], v1 = sp[1], v2 = sp[2], v3 = sp[3];
        *(short8*)&A1[r * LDA + c0]     = pack8(v0, v1);
        *(short8*)&A1[r * LDA + c0 + 8] = pack8(v2, v3);
    }
    {   // prestage A2: cols 0..63 <- nb[dst] ; cols 64..127 <- 0.5*(nf[src]+nf[dst])
        int e = tid >> 2, q = tid & 3;
        long er = row0 + e; if (er >= E) er = E - 1;
        if (q < 2) {
            int dv = dst[er];
            const float4* sp = (const float4*)(nb + (long)dv * D + q * 32);
            float4 v0 = sp[0], v1 = sp[1], v2 = sp[2], v3 = sp[3];
            float4 v4 = sp[4], v5 = sp[5], v6 = sp[6], v7 = sp[7];
            ushort* dp = &A2[e * LDA2 + q * 32];
            *(short8*)(dp)      = pack8(v0, v1);
            *(short8*)(dp + 8)  = pack8(v2, v3);
            *(short8*)(dp + 16) = pack8(v4, v5);
            *(short8*)(dp + 24) = pack8(v6, v7);
        } else {
            int sv = src[er], dv = dst[er];
            int c0 = (q - 2) * 32;
            const float4* ap = (const float4*)(nf_out + (long)sv * D + c0);
            const float4* bp = (const float4*)(nf_out + (long)dv * D + c0);
            ushort* dp = &A2[e * LDA2 + 64 + c0];
            #pragma unroll
            for (int h = 0; h < 4; ++h) {
                float4 a0 = ap[2 * h], a1 = ap[2 * h + 1];
                float4 b0 = bp[2 * h], b1 = bp[2 * h + 1];
                float4 m0 = make_float4(0.5f * (a0.x + b0.x), 0.5f * (a0.y + b0.y),
                                        0.5f * (a0.z + b0.z), 0.5f * (a0.w + b0.w));
                float4 m1 = make_float4(0.5f * (a1.x + b1.x), 0.5f * (a1.y + b1.y),
                                        0.5f * (a1.z + b1.z), 0.5f * (a1.w + b1.w));
                *(short8*)(dp + 8 * h) = pack8(m0, m1);
            }
        }
    }
    __syncthreads();

    const int w = tid >> 6, lane = tid & 63;
    const int lr = lane & 15, g = lane >> 4;
    const int arow = (16 * w + lr);

    // GEMM1: ef_h tile (16 rows x 64 cols per wave)
    short8 a0 = *(const short8*)&A1[arow * LDA + 8 * g];
    short8 a1 = *(const short8*)&A1[arow * LDA + 32 + 8 * g];
    f32x4 acc[4];
    #pragma unroll
    for (int t = 0; t < 4; ++t) {
        f32x4 z = {0.f, 0.f, 0.f, 0.f};
        short8 b0 = *(const short8*)&Bw[(16 * t + lr) * LDA + 8 * g];
        short8 b1 = *(const short8*)&Bw[(16 * t + lr) * LDA + 32 + 8 * g];
        z = __builtin_amdgcn_mfma_f32_16x16x32_bf16(a0, b0, z, 0, 0, 0);
        z = __builtin_amdgcn_mfma_f32_16x16x32_bf16(a1, b1, z, 0, 0, 0);
        acc[t] = z;
    }
    // epilogue1: A2[r][c] += ef_h  (RMW in bf16; each element owned by one lane)
    #pragma unroll
    for (int t = 0; t < 4; ++t) {
        int c = 16 * t + lr;
        #pragma unroll
        for (int reg = 0; reg < 4; ++reg) {
            int r = 16 * w + 4 * g + reg;
            int i = r * LDA2 + c;
            A2[i] = f2b(b2f(A2[i]) + acc[t][reg]);
        }
    }
    __syncthreads();

    // GEMM2: [64,128] @ [128,64]
    f32x4 acc2[4];
    #pragma unroll
    for (int t = 0; t < 4; ++t) { f32x4 z = {0.f, 0.f, 0.f, 0.f}; acc2[t] = z; }
    #pragma unroll
    for (int ks = 0; ks < 4; ++ks) {
        short8 a = *(const short8*)&A2[arow * LDA2 + 32 * ks + 8 * g];
        #pragma unroll
        for (int t = 0; t < 4; ++t) {
            short8 b = *(const short8*)&Bd[(16 * t + lr) * LDA2 + 32 * ks + 8 * g];
            acc2[t] = __builtin_amdgcn_mfma_f32_16x16x32_bf16(a, b, acc2[t], 0, 0, 0);
        }
    }
    // epilogue2: bias + relu + store
    #pragma unroll
    for (int t = 0; t < 4; ++t) {
        int c = 16 * t + lr;
        float bsum = b_dense[c] + bias_edge[c];
        #pragma unroll
        for (int reg = 0; reg < 4; ++reg) {
            long r = row0 + 16 * w + 4 * g + reg;
            if (r < E) out[r * D + c] = fmaxf(acc2[t][reg] + bsum, 0.f);
        }
    }
}

// ---------------------------------------------------------------------------
extern "C" void kernel_launch(void* const* d_in, const int* in_sizes, int n_in,
                              void* d_out, int out_size, void* d_ws, size_t ws_size,
                              hipStream_t stream) {
    const float* nf        = (const float*)d_in[0];
    const float* ef        = (const float*)d_in[1];
    const int*   src       = (const int*)d_in[2];
    const int*   dst       = (const int*)d_in[3];
    const float* W_node    = (const float*)d_in[4];
    const float* W_edge    = (const float*)d_in[5];
    const float* bias_node = (const float*)d_in[6];
    const float* bias_edge = (const float*)d_in[7];
    const float* W_dense   = (const float*)d_in[8];
    const float* b_dense   = (const float*)d_in[9];

    const int N = in_sizes[0] / D;
    const int E = in_sizes[1] / D;

    float* nf_out = (float*)d_out;
    float* ef_out = (float*)d_out + (size_t)N * D;

    float* nb  = (float*)d_ws;            // N*D floats
    float* deg = nb + (size_t)N * D;      // N floats

    hipMemsetAsync(d_ws, 0, ((size_t)N * D + N) * sizeof(float), stream);

    node_proj_kernel<<<(N + 15) / 16, 256, 0, stream>>>(nf, W_node, bias_node, nf_out, N);
    edge_proj_accum_kernel<<<(E + 63) / 64, 256, 0, stream>>>(ef, dst, W_edge, nb, deg, E);
    finalize_nb_kernel<<<(int)(((size_t)N * D + 255) / 256), 256, 0, stream>>>(nb, deg, (long)N * D);
    edge_out_kernel<<<(E + 63) / 64, 256, 0, stream>>>(ef, src, dst, W_edge, nb, nf_out,
                                                       W_dense, b_dense, bias_edge, ef_out, E);
}